// Round 3
// baseline (111809.839 us; speedup 1.0000x reference)
//
#include <hip/hip_runtime.h>
#include <math.h>

#define Bq 256
#define Tq 200
#define INq 33
#define Hq 2048
#define OUTq 4

#define BM 32
#define BN 64
#define BK 64
#define HALFK 1024
#define NST (HALFK / BK)        // 16 stages per K-half

// LDS layout (float offsets inside one 96 KB block):
//   As[half][buf] : 32 x 64  at ((h*2+b)*2048)
//   Bs[half][buf] : 64 x 64  at (8192 + (h*2+b)*4096)
//   Red           : reuses As[1][0] (offset 4096), only used after K-loop
#define AS_OFF(h,b) (((h)*2+(b))*2048)
#define BS_OFF(h,b) (8192 + ((h)*2+(b))*4096)
#define RED_OFF 4096
#define SMEM_FLOATS 24576       // 96 KB

// XOR swizzle: float-index k (multiple of 4) swizzled within a 64-float row.
// key derived from row bits that VARY across the lanes of one read inst.
__device__ __forceinline__ int asIdx(int base, int m, int k) {
  return base + m * 64 + (k ^ (((m >> 1) & 7) << 2));
}
__device__ __forceinline__ int bsIdx(int base, int j, int k) {
  return base + j * 64 + (k ^ (((j >> 2) & 7) << 2));
}

// ---------------------------------------------------------------------------
// Output head (used by tail kernel): out_o[r, tp, :] = softmax(h_row @ Wh2o^T)
// ---------------------------------------------------------------------------
__global__ __launch_bounds__(256) void proj_tail(
    const float* __restrict__ hbase, size_t rstride,
    const float* __restrict__ Wh2o, float* __restrict__ out_o, int tp)
{
  const int tid = threadIdx.x;
  const int r  = blockIdx.x * 64 + (tid >> 2);
  const int p4 = tid & 3;
  const float* hp = hbase + (size_t)r * rstride;
  float acc0 = 0.f, acc1 = 0.f, acc2 = 0.f, acc3 = 0.f;
  const int k0 = p4 * 512;
#pragma unroll 4
  for (int k = k0; k < k0 + 512; k += 4) {
    float4 hv = *(const float4*)(hp + k);
    float4 w0 = *(const float4*)(Wh2o + 0 * Hq + k);
    float4 w1 = *(const float4*)(Wh2o + 1 * Hq + k);
    float4 w2 = *(const float4*)(Wh2o + 2 * Hq + k);
    float4 w3 = *(const float4*)(Wh2o + 3 * Hq + k);
    acc0 = fmaf(hv.x, w0.x, fmaf(hv.y, w0.y, fmaf(hv.z, w0.z, fmaf(hv.w, w0.w, acc0))));
    acc1 = fmaf(hv.x, w1.x, fmaf(hv.y, w1.y, fmaf(hv.z, w1.z, fmaf(hv.w, w1.w, acc1))));
    acc2 = fmaf(hv.x, w2.x, fmaf(hv.y, w2.y, fmaf(hv.z, w2.z, fmaf(hv.w, w2.w, acc2))));
    acc3 = fmaf(hv.x, w3.x, fmaf(hv.y, w3.y, fmaf(hv.z, w3.z, fmaf(hv.w, w3.w, acc3))));
  }
  acc0 += __shfl_xor(acc0, 1); acc1 += __shfl_xor(acc1, 1);
  acc2 += __shfl_xor(acc2, 1); acc3 += __shfl_xor(acc3, 1);
  acc0 += __shfl_xor(acc0, 2); acc1 += __shfl_xor(acc1, 2);
  acc2 += __shfl_xor(acc2, 2); acc3 += __shfl_xor(acc3, 2);
  if (p4 == 0) {
    float m  = fmaxf(fmaxf(acc0, acc1), fmaxf(acc2, acc3));
    float e0 = expf(acc0 - m), e1 = expf(acc1 - m);
    float e2 = expf(acc2 - m), e3 = expf(acc3 - m);
    float inv = 1.0f / (e0 + e1 + e2 + e3);
    float* op = out_o + ((size_t)r * Tq + tp) * OUTq;
    op[0] = e0 * inv; op[1] = e1 * inv; op[2] = e2 * inv; op[3] = e3 * inv;
  }
}

// ---------------------------------------------------------------------------
// One step. 256 WGs x 512 threads (1 WG/CU).
//  - WG r also computes the softmax head for step t-1 (batch row r) at entry.
//  - GEMM: 32x64 tile, in-WG split-K x2 (halves of 1024), BK=64, double-buffered
//    swizzled LDS, 2x4 micro-tile, 4-k-dot inner blocks (6 LDS reads / 32 FMA).
//  - h_{t-1} read from contiguous slab (d_ws ping-pong) when available.
// ---------------------------------------------------------------------------
__global__ __launch_bounds__(512) void rnn_step(
    const float* __restrict__ x, const float* __restrict__ noise,
    const float* __restrict__ Wi2h, const float* __restrict__ Wrec,
    const float* __restrict__ Wh2o, float* __restrict__ out_h,
    float* __restrict__ out_o, const float* __restrict__ slabP,
    float* __restrict__ slabT, int t)
{
  __shared__ float smem[SMEM_FLOATS];

  const int wg  = blockIdx.x;
  const int tid = threadIdx.x;

  // XCD-chunked swizzle: XCD c owns col-tiles [4c, 4c+4) -> Wrec slice L2-hot
  const int L = (wg & 7) * 32 + (wg >> 3);
  const int tileCol = L >> 3;     // 0..31
  const int tileRow = L & 7;      // 0..7

  const int half = tid >> 8;      // K half
  const int ht   = tid & 255;
  const int tx   = ht & 15;       // col quad
  const int ty   = ht >> 4;       // row pair
  const int b0   = tileRow * BM + ty * 2;
  const int j0   = tileCol * BN + tx * 4;
  const int kb   = half * HALFK;

  // h_{t-1} source: contiguous slab if provided, else strided out_h
  const float* hPrev = slabP ? slabP : (out_h + (size_t)(t > 0 ? t - 1 : 0) * Hq);
  const size_t hStr  = slabP ? (size_t)Hq : (size_t)Tq * Hq;

  // ---- early loads: noise + h_prev (decay term) ----
  const float* nzp = noise + ((size_t)t * Bq + b0) * Hq + j0;
  float4 nz0 = *(const float4*)nzp;
  float4 nz1 = *(const float4*)(nzp + Hq);
  float4 hp0 = make_float4(0.f, 0.f, 0.f, 0.f), hp1 = hp0;
  if (t > 0) {
    hp0 = *(const float4*)(hPrev + (size_t)b0 * hStr + j0);
    hp1 = *(const float4*)(hPrev + (size_t)(b0 + 1) * hStr + j0);
  }

  // ---- staging geometry (same k-quad for all 6 loads of a thread) ----
  const int kq   = (ht & 15) * 4;           // 0..60
  const int mrow = ht >> 4;                  // 0..15
  const float* Ag0 = hPrev + (size_t)(tileRow * BM + mrow) * hStr + kb + kq;
  const float* Ag1 = hPrev + (size_t)(tileRow * BM + mrow + 16) * hStr + kb + kq;
  const float* Bg0 = Wrec + (size_t)(tileCol * BN + mrow +  0) * Hq + kb + kq;
  const float* Bg1 = Wrec + (size_t)(tileCol * BN + mrow + 16) * Hq + kb + kq;
  const float* Bg2 = Wrec + (size_t)(tileCol * BN + mrow + 32) * Hq + kb + kq;
  const float* Bg3 = Wrec + (size_t)(tileCol * BN + mrow + 48) * Hq + kb + kq;

  float4 sA0, sA1, sB0, sB1, sB2, sB3;
  if (t > 0) {                               // issue prologue stage loads NOW
    sA0 = *(const float4*)Ag0;  sA1 = *(const float4*)Ag1;
    sB0 = *(const float4*)Bg0;  sB1 = *(const float4*)Bg1;
    sB2 = *(const float4*)Bg2;  sB3 = *(const float4*)Bg3;
  }

  // ---- output head for step t-1 (batch row = wg), overlaps stage latency ----
  if (t > 0) {
    const int i4 = tid * 4;
    float4 hv = *(const float4*)(hPrev + (size_t)wg * hStr + i4);
    float4 w0 = *(const float4*)(Wh2o + 0 * Hq + i4);
    float4 w1 = *(const float4*)(Wh2o + 1 * Hq + i4);
    float4 w2 = *(const float4*)(Wh2o + 2 * Hq + i4);
    float4 w3 = *(const float4*)(Wh2o + 3 * Hq + i4);
    float a0 = fmaf(hv.x, w0.x, fmaf(hv.y, w0.y, fmaf(hv.z, w0.z, hv.w * w0.w)));
    float a1 = fmaf(hv.x, w1.x, fmaf(hv.y, w1.y, fmaf(hv.z, w1.z, hv.w * w1.w)));
    float a2 = fmaf(hv.x, w2.x, fmaf(hv.y, w2.y, fmaf(hv.z, w2.z, hv.w * w2.w)));
    float a3 = fmaf(hv.x, w3.x, fmaf(hv.y, w3.y, fmaf(hv.z, w3.z, hv.w * w3.w)));
#pragma unroll
    for (int m = 1; m <= 32; m <<= 1) {
      a0 += __shfl_xor(a0, m); a1 += __shfl_xor(a1, m);
      a2 += __shfl_xor(a2, m); a3 += __shfl_xor(a3, m);
    }
    if ((tid & 63) == 0) {
      const int w = tid >> 6;
      smem[w * 4 + 0] = a0; smem[w * 4 + 1] = a1;
      smem[w * 4 + 2] = a2; smem[w * 4 + 3] = a3;
    }
    __syncthreads();
    if (tid == 0) {
      float s0 = 0.f, s1 = 0.f, s2 = 0.f, s3 = 0.f;
#pragma unroll
      for (int w = 0; w < 8; ++w) {          // fixed order -> deterministic
        s0 += smem[w * 4 + 0]; s1 += smem[w * 4 + 1];
        s2 += smem[w * 4 + 2]; s3 += smem[w * 4 + 3];
      }
      float m  = fmaxf(fmaxf(s0, s1), fmaxf(s2, s3));
      float e0 = expf(s0 - m), e1 = expf(s1 - m);
      float e2 = expf(s2 - m), e3 = expf(s3 - m);
      float inv = 1.0f / (e0 + e1 + e2 + e3);
      float* op = out_o + ((size_t)wg * Tq + (t - 1)) * OUTq;
      op[0] = e0 * inv; op[1] = e1 * inv; op[2] = e2 * inv; op[3] = e3 * inv;
    }
    __syncthreads();                          // protect smem[0..31] before staging
  }

  float acc00 = 0.f, acc01 = 0.f, acc02 = 0.f, acc03 = 0.f;
  float acc10 = 0.f, acc11 = 0.f, acc12 = 0.f, acc13 = 0.f;

  if (t > 0) {
    const int asB[2] = { AS_OFF(half, 0), AS_OFF(half, 1) };
    const int bsB[2] = { BS_OFF(half, 0), BS_OFF(half, 1) };
    const int keyA = (ty & 7) << 2;           // same for both A rows of a thread
    const int keyB = (tx & 7) << 2;           // same for all 4 B rows of a thread
    const int rowA0 = ty * 128;               // (ty*2)*64
    const int rowB  = tx * 256;               // (tx*4)*64

    // prologue: write stage 0
    {
      *(float4*)&smem[asIdx(asB[0], mrow,      kq)] = sA0;
      *(float4*)&smem[asIdx(asB[0], mrow + 16, kq)] = sA1;
      *(float4*)&smem[bsIdx(bsB[0], mrow,      kq)] = sB0;
      *(float4*)&smem[bsIdx(bsB[0], mrow + 16, kq)] = sB1;
      *(float4*)&smem[bsIdx(bsB[0], mrow + 32, kq)] = sB2;
      *(float4*)&smem[bsIdx(bsB[0], mrow + 48, kq)] = sB3;
    }
    __syncthreads();

    for (int s = 0; s < NST; ++s) {
      const int buf = s & 1;
      if (s + 1 < NST) {                      // prefetch next stage
        const int o = (s + 1) * BK;
        sA0 = *(const float4*)(Ag0 + o);  sA1 = *(const float4*)(Ag1 + o);
        sB0 = *(const float4*)(Bg0 + o);  sB1 = *(const float4*)(Bg1 + o);
        sB2 = *(const float4*)(Bg2 + o);  sB3 = *(const float4*)(Bg3 + o);
      }
      const float* aB = smem + asB[buf] + rowA0;
      const float* bB = smem + bsB[buf] + rowB;
#pragma unroll
      for (int kk = 0; kk < BK; kk += 4) {
        const int ka = kk ^ keyA;             // loop-invariant parts hoisted
        const int kbo = kk ^ keyB;
        float4 a0 = *(const float4*)(aB + ka);
        float4 a1 = *(const float4*)(aB + 64 + ka);
        float4 v0 = *(const float4*)(bB + kbo);
        float4 v1 = *(const float4*)(bB + 64 + kbo);
        float4 v2 = *(const float4*)(bB + 128 + kbo);
        float4 v3 = *(const float4*)(bB + 192 + kbo);
        acc00 = fmaf(a0.x, v0.x, acc00); acc00 = fmaf(a0.y, v0.y, acc00);
        acc00 = fmaf(a0.z, v0.z, acc00); acc00 = fmaf(a0.w, v0.w, acc00);
        acc01 = fmaf(a0.x, v1.x, acc01); acc01 = fmaf(a0.y, v1.y, acc01);
        acc01 = fmaf(a0.z, v1.z, acc01); acc01 = fmaf(a0.w, v1.w, acc01);
        acc02 = fmaf(a0.x, v2.x, acc02); acc02 = fmaf(a0.y, v2.y, acc02);
        acc02 = fmaf(a0.z, v2.z, acc02); acc02 = fmaf(a0.w, v2.w, acc02);
        acc03 = fmaf(a0.x, v3.x, acc03); acc03 = fmaf(a0.y, v3.y, acc03);
        acc03 = fmaf(a0.z, v3.z, acc03); acc03 = fmaf(a0.w, v3.w, acc03);
        acc10 = fmaf(a1.x, v0.x, acc10); acc10 = fmaf(a1.y, v0.y, acc10);
        acc10 = fmaf(a1.z, v0.z, acc10); acc10 = fmaf(a1.w, v0.w, acc10);
        acc11 = fmaf(a1.x, v1.x, acc11); acc11 = fmaf(a1.y, v1.y, acc11);
        acc11 = fmaf(a1.z, v1.z, acc11); acc11 = fmaf(a1.w, v1.w, acc11);
        acc12 = fmaf(a1.x, v2.x, acc12); acc12 = fmaf(a1.y, v2.y, acc12);
        acc12 = fmaf(a1.z, v2.z, acc12); acc12 = fmaf(a1.w, v2.w, acc12);
        acc13 = fmaf(a1.x, v3.x, acc13); acc13 = fmaf(a1.y, v3.y, acc13);
        acc13 = fmaf(a1.z, v3.z, acc13); acc13 = fmaf(a1.w, v3.w, acc13);
      }
      if (s + 1 < NST) {                      // write next stage
        const int nb = buf ^ 1;
        *(float4*)&smem[asIdx(asB[nb], mrow,      kq)] = sA0;
        *(float4*)&smem[asIdx(asB[nb], mrow + 16, kq)] = sA1;
        *(float4*)&smem[bsIdx(bsB[nb], mrow,      kq)] = sB0;
        *(float4*)&smem[bsIdx(bsB[nb], mrow + 16, kq)] = sB1;
        *(float4*)&smem[bsIdx(bsB[nb], mrow + 32, kq)] = sB2;
        *(float4*)&smem[bsIdx(bsB[nb], mrow + 48, kq)] = sB3;
      }
      __syncthreads();
    }
  }

  // half 1: fused input projection (IN=33), then dump partials to Red
  if (half == 1) {
    const float* xr0 = x + ((size_t)b0 * Tq + t) * INq;
    const float* xr1 = xr0 + (size_t)Tq * INq;
    const float* wi  = Wi2h + (size_t)j0 * INq;
#pragma unroll
    for (int i = 0; i < INq; ++i) {
      float x0 = xr0[i], x1 = xr1[i];
      float u0 = wi[i], u1 = wi[INq + i], u2 = wi[2 * INq + i], u3 = wi[3 * INq + i];
      acc00 = fmaf(x0, u0, acc00); acc01 = fmaf(x0, u1, acc01);
      acc02 = fmaf(x0, u2, acc02); acc03 = fmaf(x0, u3, acc03);
      acc10 = fmaf(x1, u0, acc10); acc11 = fmaf(x1, u1, acc11);
      acc12 = fmaf(x1, u2, acc12); acc13 = fmaf(x1, u3, acc13);
    }
    float* rd = smem + RED_OFF;               // reuses As[1][0]; safe post-loop
    rd[0 * 256 + ht] = acc00; rd[1 * 256 + ht] = acc01;
    rd[2 * 256 + ht] = acc02; rd[3 * 256 + ht] = acc03;
    rd[4 * 256 + ht] = acc10; rd[5 * 256 + ht] = acc11;
    rd[6 * 256 + ht] = acc12; rd[7 * 256 + ht] = acc13;
  }
  __syncthreads();

  if (half == 0) {
    const float* rd = smem + RED_OFF;
    acc00 += rd[0 * 256 + ht]; acc01 += rd[1 * 256 + ht];
    acc02 += rd[2 * 256 + ht]; acc03 += rd[3 * 256 + ht];
    acc10 += rd[4 * 256 + ht]; acc11 += rd[5 * 256 + ht];
    acc12 += rd[6 * 256 + ht]; acc13 += rd[7 * 256 + ht];

    float4 o0, o1;
    o0.x = fmaf(fmaxf(acc00 + nz0.x, 0.f), 0.1f, 0.9f * hp0.x);
    o0.y = fmaf(fmaxf(acc01 + nz0.y, 0.f), 0.1f, 0.9f * hp0.y);
    o0.z = fmaf(fmaxf(acc02 + nz0.z, 0.f), 0.1f, 0.9f * hp0.z);
    o0.w = fmaf(fmaxf(acc03 + nz0.w, 0.f), 0.1f, 0.9f * hp0.w);
    o1.x = fmaf(fmaxf(acc10 + nz1.x, 0.f), 0.1f, 0.9f * hp1.x);
    o1.y = fmaf(fmaxf(acc11 + nz1.y, 0.f), 0.1f, 0.9f * hp1.y);
    o1.z = fmaf(fmaxf(acc12 + nz1.z, 0.f), 0.1f, 0.9f * hp1.z);
    o1.w = fmaf(fmaxf(acc13 + nz1.w, 0.f), 0.1f, 0.9f * hp1.w);

    *(float4*)(out_h + ((size_t)b0 * Tq + t) * Hq + j0) = o0;
    *(float4*)(out_h + ((size_t)(b0 + 1) * Tq + t) * Hq + j0) = o1;
    if (slabT) {
      *(float4*)(slabT + (size_t)b0 * Hq + j0) = o0;
      *(float4*)(slabT + (size_t)(b0 + 1) * Hq + j0) = o1;
    }
  }
}

extern "C" void kernel_launch(void* const* d_in, const int* in_sizes, int n_in,
                              void* d_out, int out_size, void* d_ws, size_t ws_size,
                              hipStream_t stream) {
  const float* x     = (const float*)d_in[0];
  const float* noise = (const float*)d_in[1];
  const float* Wi2h  = (const float*)d_in[2];
  const float* Wrec  = (const float*)d_in[3];
  const float* Wh2o  = (const float*)d_in[4];
  float* out_h = (float*)d_out;
  float* out_o = out_h + (size_t)Bq * Tq * Hq;

  const bool use_ws = ws_size >= (size_t)2 * Bq * Hq * sizeof(float);
  float* slab0 = (float*)d_ws;
  float* slab1 = slab0 + (size_t)Bq * Hq;

  for (int t = 0; t < Tq; ++t) {
    const float* sp = (t > 0 && use_ws) ? (((t - 1) & 1) ? slab1 : slab0) : nullptr;
    float*       st = use_ws ? ((t & 1) ? slab1 : slab0) : nullptr;
    rnn_step<<<256, 512, 0, stream>>>(x, noise, Wi2h, Wrec, Wh2o,
                                      out_h, out_o, sp, st, t);
  }
  const float* hb = use_ws ? slab1 : (out_h + (size_t)(Tq - 1) * Hq);
  const size_t rs = use_ws ? (size_t)Hq : (size_t)Tq * Hq;
  proj_tail<<<4, 256, 0, stream>>>(hb, rs, Wh2o, out_o, Tq - 1);
}

// Round 4
// 10701.455 us; speedup vs baseline: 10.4481x; 10.4481x over previous
//
#include <hip/hip_runtime.h>
#include <math.h>

#define Bq 256
#define Tq 200
#define INq 33
#define Hq 2048
#define OUTq 4

#define BKq 32
#define NST 16          // stages per K-quarter: 512 / 32

// dot4 accumulate
#define DOT4(ACC, Av, Bv) \
  ACC = fmaf((Av).x, (Bv).x, ACC); ACC = fmaf((Av).y, (Bv).y, ACC); \
  ACC = fmaf((Av).z, (Bv).z, ACC); ACC = fmaf((Av).w, (Bv).w, ACC)

// XOR swizzle inside a 32-float row: spreads k-columns across banks per row-group
__device__ __forceinline__ int swz(int row, int k) {
  return k ^ (((row >> 2) & 7) << 2);
}

// ---------------------------------------------------------------------------
// tail: out_o[r, tp, :] = softmax(h_row @ Wh2o^T) for the final step
// ---------------------------------------------------------------------------
__global__ __launch_bounds__(256) void proj_tail(
    const float* __restrict__ hbase, size_t rstride,
    const float* __restrict__ Wh2o, float* __restrict__ out_o, int tp)
{
  const int tid = threadIdx.x;
  const int r  = blockIdx.x * 64 + (tid >> 2);
  const int p4 = tid & 3;
  const float* hp = hbase + (size_t)r * rstride;
  float a0 = 0.f, a1 = 0.f, a2 = 0.f, a3 = 0.f;
  const int k0 = p4 * 512;
#pragma unroll 4
  for (int k = k0; k < k0 + 512; k += 4) {
    float4 hv = *(const float4*)(hp + k);
    float4 w0 = *(const float4*)(Wh2o + 0 * Hq + k);
    float4 w1 = *(const float4*)(Wh2o + 1 * Hq + k);
    float4 w2 = *(const float4*)(Wh2o + 2 * Hq + k);
    float4 w3 = *(const float4*)(Wh2o + 3 * Hq + k);
    DOT4(a0, hv, w0); DOT4(a1, hv, w1); DOT4(a2, hv, w2); DOT4(a3, hv, w3);
  }
  a0 += __shfl_xor(a0, 1); a1 += __shfl_xor(a1, 1);
  a2 += __shfl_xor(a2, 1); a3 += __shfl_xor(a3, 1);
  a0 += __shfl_xor(a0, 2); a1 += __shfl_xor(a1, 2);
  a2 += __shfl_xor(a2, 2); a3 += __shfl_xor(a3, 2);
  if (p4 == 0) {
    float m  = fmaxf(fmaxf(a0, a1), fmaxf(a2, a3));
    float e0 = expf(a0 - m), e1 = expf(a1 - m);
    float e2 = expf(a2 - m), e3 = expf(a3 - m);
    float inv = 1.0f / (e0 + e1 + e2 + e3);
    float* op = out_o + ((size_t)r * Tq + tp) * OUTq;
    op[0] = e0 * inv; op[1] = e1 * inv; op[2] = e2 * inv; op[3] = e3 * inv;
  }
}

// ---------------------------------------------------------------------------
// One step. 256 WGs x 512 threads (1 WG/CU, 96KB LDS).
// Quarter q (128 thr) computes k in [512q, 512q+512); 32x64 tile, 4x4 micro,
// along-K b128 fragments from natural-row-major swizzled LDS tiles.
// WG wg also computes the softmax head for batch row wg at step t-1.
// Fixed-order split-K combine in LDS -> deterministic.
// ---------------------------------------------------------------------------
__global__ __launch_bounds__(512, 2) void rnn_step(
    const float* __restrict__ x, const float* __restrict__ noise,
    const float* __restrict__ Wi2h, const float* __restrict__ Wrec,
    const float* __restrict__ Wh2o, float* __restrict__ out_h,
    float* __restrict__ out_o, const float* __restrict__ slabP,
    float* __restrict__ slabT, int t)
{
  // A[q][buf]: 32x32 at q*2048 + buf*1024           (8192 floats)
  // B[q][buf]: 64x32 at 8192 + q*4096 + buf*2048    (16384 floats)
  // Red: reuses [0, 7680) after the K-loop
  __shared__ float smem[24576];

  const int wg  = blockIdx.x;
  const int tid = threadIdx.x;

  // XCD-chunked swizzle: XCD c owns col-tiles [4c, 4c+4) -> 2MB Wrec panel L2-hot
  const int L  = (wg & 7) * 32 + (wg >> 3);
  const int TC = L >> 3;          // 0..31
  const int TR = L & 7;           // 0..7

  const int q  = tid >> 7;        // K-quarter 0..3
  const int qt = tid & 127;
  const int tx = qt & 15;         // n-quad
  const int ty = qt >> 4;         // m-quad (0..7)
  const int m0 = ty * 4, n0 = tx * 4;
  const int b0 = TR * 32 + m0;    // batch row base
  const int j0 = TC * 64 + n0;    // hidden col base
  const int kb = q * 512;

  const float* hPrev = slabP ? slabP : out_h + (size_t)(t > 0 ? t - 1 : 0) * Hq;
  const size_t hStr  = slabP ? (size_t)Hq : (size_t)Tq * Hq;

  // staging maps (per quarter)
  const int sm  = qt & 31;            // A row; k-chunk of 8
  const int skh = (qt >> 5) * 8;
  const int sn  = qt >> 1;            // B row; k-chunk of 16
  const int snk = (qt & 1) * 16;
  const float* gA = hPrev + (size_t)(TR * 32 + sm) * hStr + kb + skh;
  const float* gB = Wrec + (size_t)(TC * 64 + sn) * Hq + kb + snk;

  float4 sA0, sA1, sB0, sB1, sB2, sB3;
  if (t > 0) {                        // issue stage-0 loads first (overlap proj)
    sA0 = *(const float4*)(gA);      sA1 = *(const float4*)(gA + 4);
    sB0 = *(const float4*)(gB);      sB1 = *(const float4*)(gB + 4);
    sB2 = *(const float4*)(gB + 8);  sB3 = *(const float4*)(gB + 12);
  }

  // ---- softmax head for step t-1, batch row wg (all 512 threads) ----
  if (t > 0) {
    const int i4 = tid * 4;
    float4 hv = *(const float4*)(hPrev + (size_t)wg * hStr + i4);
    float4 w0 = *(const float4*)(Wh2o + 0 * Hq + i4);
    float4 w1 = *(const float4*)(Wh2o + 1 * Hq + i4);
    float4 w2 = *(const float4*)(Wh2o + 2 * Hq + i4);
    float4 w3 = *(const float4*)(Wh2o + 3 * Hq + i4);
    float a0 = 0.f, a1 = 0.f, a2 = 0.f, a3 = 0.f;
    DOT4(a0, hv, w0); DOT4(a1, hv, w1); DOT4(a2, hv, w2); DOT4(a3, hv, w3);
#pragma unroll
    for (int m = 1; m <= 32; m <<= 1) {
      a0 += __shfl_xor(a0, m); a1 += __shfl_xor(a1, m);
      a2 += __shfl_xor(a2, m); a3 += __shfl_xor(a3, m);
    }
    if ((tid & 63) == 0) {
      const int w = tid >> 6;
      smem[w * 4 + 0] = a0; smem[w * 4 + 1] = a1;
      smem[w * 4 + 2] = a2; smem[w * 4 + 3] = a3;
    }
    __syncthreads();
    if (tid == 0) {
      float s0 = 0.f, s1 = 0.f, s2 = 0.f, s3 = 0.f;
#pragma unroll
      for (int w = 0; w < 8; ++w) {   // fixed order
        s0 += smem[w * 4 + 0]; s1 += smem[w * 4 + 1];
        s2 += smem[w * 4 + 2]; s3 += smem[w * 4 + 3];
      }
      float m  = fmaxf(fmaxf(s0, s1), fmaxf(s2, s3));
      float e0 = expf(s0 - m), e1 = expf(s1 - m);
      float e2 = expf(s2 - m), e3 = expf(s3 - m);
      float inv = 1.0f / (e0 + e1 + e2 + e3);
      float* op = out_o + ((size_t)wg * Tq + (t - 1)) * OUTq;
      op[0] = e0 * inv; op[1] = e1 * inv; op[2] = e2 * inv; op[3] = e3 * inv;
    }
    __syncthreads();                  // smem[0..31] dead before staging
  }

  float acc00 = 0.f, acc01 = 0.f, acc02 = 0.f, acc03 = 0.f;
  float acc10 = 0.f, acc11 = 0.f, acc12 = 0.f, acc13 = 0.f;
  float acc20 = 0.f, acc21 = 0.f, acc22 = 0.f, acc23 = 0.f;
  float acc30 = 0.f, acc31 = 0.f, acc32 = 0.f, acc33 = 0.f;

  if (t > 0) {
    // prologue: write stage 0 (buf 0)
    {
      float* aL = smem + q * 2048;
      float* bL = smem + 8192 + q * 4096;
      *(float4*)(aL + sm * 32 + swz(sm, skh))      = sA0;
      *(float4*)(aL + sm * 32 + swz(sm, skh + 4))  = sA1;
      *(float4*)(bL + sn * 32 + swz(sn, snk))      = sB0;
      *(float4*)(bL + sn * 32 + swz(sn, snk + 4))  = sB1;
      *(float4*)(bL + sn * 32 + swz(sn, snk + 8))  = sB2;
      *(float4*)(bL + sn * 32 + swz(sn, snk + 12)) = sB3;
    }
    __syncthreads();

    const int aKey = ty << 2;
    const int bKey = (tx & 7) << 2;

    for (int s = 0; s < NST; ++s) {
      const int buf = s & 1;
      if (s + 1 < NST) {              // prefetch next stage into regs
        const int o = (s + 1) * BKq;
        sA0 = *(const float4*)(gA + o);      sA1 = *(const float4*)(gA + o + 4);
        sB0 = *(const float4*)(gB + o);      sB1 = *(const float4*)(gB + o + 4);
        sB2 = *(const float4*)(gB + o + 8);  sB3 = *(const float4*)(gB + o + 12);
      }
      const float* aT = smem + q * 2048 + buf * 1024 + ty * 128;
      const float* bT = smem + 8192 + q * 4096 + buf * 2048 + tx * 128;
#pragma unroll
      for (int k4 = 0; k4 < BKq; k4 += 4) {
        const float* ap = aT + (k4 ^ aKey);
        const float* bp = bT + (k4 ^ bKey);
        float4 A0 = *(const float4*)(ap);
        float4 A1 = *(const float4*)(ap + 32);
        float4 A2 = *(const float4*)(ap + 64);
        float4 A3 = *(const float4*)(ap + 96);
        float4 Bv0 = *(const float4*)(bp);
        float4 Bv1 = *(const float4*)(bp + 32);
        float4 Bv2 = *(const float4*)(bp + 64);
        float4 Bv3 = *(const float4*)(bp + 96);
        DOT4(acc00, A0, Bv0); DOT4(acc01, A0, Bv1); DOT4(acc02, A0, Bv2); DOT4(acc03, A0, Bv3);
        DOT4(acc10, A1, Bv0); DOT4(acc11, A1, Bv1); DOT4(acc12, A1, Bv2); DOT4(acc13, A1, Bv3);
        DOT4(acc20, A2, Bv0); DOT4(acc21, A2, Bv1); DOT4(acc22, A2, Bv2); DOT4(acc23, A2, Bv3);
        DOT4(acc30, A3, Bv0); DOT4(acc31, A3, Bv1); DOT4(acc32, A3, Bv2); DOT4(acc33, A3, Bv3);
      }
      if (s + 1 < NST) {              // write next stage to other buffer
        float* aL = smem + q * 2048 + (buf ^ 1) * 1024;
        float* bL = smem + 8192 + q * 4096 + (buf ^ 1) * 2048;
        *(float4*)(aL + sm * 32 + swz(sm, skh))      = sA0;
        *(float4*)(aL + sm * 32 + swz(sm, skh + 4))  = sA1;
        *(float4*)(bL + sn * 32 + swz(sn, snk))      = sB0;
        *(float4*)(bL + sn * 32 + swz(sn, snk + 4))  = sB1;
        *(float4*)(bL + sn * 32 + swz(sn, snk + 8))  = sB2;
        *(float4*)(bL + sn * 32 + swz(sn, snk + 12)) = sB3;
      }
      __syncthreads();
    }
  }

  // ---- input projection, i-range split across quarters ----
  {
    const int ilo = q * 8;
    const int ihi = (q == 3) ? INq : (ilo + 8);
    const float* xb = x + (size_t)b0 * Tq * INq + (size_t)t * INq;
    const float* wv = Wi2h + (size_t)j0 * INq;
    const size_t xs = (size_t)Tq * INq;
    for (int i = ilo; i < ihi; ++i) {
      float x0 = xb[i], x1 = xb[xs + i], x2 = xb[2 * xs + i], x3 = xb[3 * xs + i];
      float w0 = wv[i], w1 = wv[INq + i], w2 = wv[2 * INq + i], w3 = wv[3 * INq + i];
      acc00 = fmaf(x0, w0, acc00); acc01 = fmaf(x0, w1, acc01);
      acc02 = fmaf(x0, w2, acc02); acc03 = fmaf(x0, w3, acc03);
      acc10 = fmaf(x1, w0, acc10); acc11 = fmaf(x1, w1, acc11);
      acc12 = fmaf(x1, w2, acc12); acc13 = fmaf(x1, w3, acc13);
      acc20 = fmaf(x2, w0, acc20); acc21 = fmaf(x2, w1, acc21);
      acc22 = fmaf(x2, w2, acc22); acc23 = fmaf(x2, w3, acc23);
      acc30 = fmaf(x3, w0, acc30); acc31 = fmaf(x3, w1, acc31);
      acc32 = fmaf(x3, w2, acc32); acc33 = fmaf(x3, w3, acc33);
    }
  }

  // ---- split-K combine via LDS (fixed order q1,q2,q3) ----
  if (q != 0) {
    float* rd = smem + (q - 1) * 2560 + qt * 20;
    *(float4*)(rd + 0)  = make_float4(acc00, acc01, acc02, acc03);
    *(float4*)(rd + 4)  = make_float4(acc10, acc11, acc12, acc13);
    *(float4*)(rd + 8)  = make_float4(acc20, acc21, acc22, acc23);
    *(float4*)(rd + 12) = make_float4(acc30, acc31, acc32, acc33);
  }
  __syncthreads();

  if (q == 0) {
#pragma unroll
    for (int p = 0; p < 3; ++p) {
      const float* rd = smem + p * 2560 + qt * 20;
      float4 r0 = *(const float4*)(rd + 0),  r1 = *(const float4*)(rd + 4);
      float4 r2 = *(const float4*)(rd + 8),  r3 = *(const float4*)(rd + 12);
      acc00 += r0.x; acc01 += r0.y; acc02 += r0.z; acc03 += r0.w;
      acc10 += r1.x; acc11 += r1.y; acc12 += r1.z; acc13 += r1.w;
      acc20 += r2.x; acc21 += r2.y; acc22 += r2.z; acc23 += r2.w;
      acc30 += r3.x; acc31 += r3.y; acc32 += r3.z; acc33 += r3.w;
    }

    const float* nzb = noise + ((size_t)t * Bq + b0) * Hq + j0;
    float4 nz0 = *(const float4*)(nzb);
    float4 nz1 = *(const float4*)(nzb + Hq);
    float4 nz2 = *(const float4*)(nzb + 2 * Hq);
    float4 nz3 = *(const float4*)(nzb + 3 * Hq);
    float4 hp0 = make_float4(0.f,0.f,0.f,0.f), hp1 = hp0, hp2 = hp0, hp3 = hp0;
    if (t > 0) {
      hp0 = *(const float4*)(hPrev + (size_t)(b0 + 0) * hStr + j0);
      hp1 = *(const float4*)(hPrev + (size_t)(b0 + 1) * hStr + j0);
      hp2 = *(const float4*)(hPrev + (size_t)(b0 + 2) * hStr + j0);
      hp3 = *(const float4*)(hPrev + (size_t)(b0 + 3) * hStr + j0);
    }

    float4 o0, o1, o2, o3;
    o0.x = fmaf(fmaxf(acc00 + nz0.x, 0.f), 0.1f, 0.9f * hp0.x);
    o0.y = fmaf(fmaxf(acc01 + nz0.y, 0.f), 0.1f, 0.9f * hp0.y);
    o0.z = fmaf(fmaxf(acc02 + nz0.z, 0.f), 0.1f, 0.9f * hp0.z);
    o0.w = fmaf(fmaxf(acc03 + nz0.w, 0.f), 0.1f, 0.9f * hp0.w);
    o1.x = fmaf(fmaxf(acc10 + nz1.x, 0.f), 0.1f, 0.9f * hp1.x);
    o1.y = fmaf(fmaxf(acc11 + nz1.y, 0.f), 0.1f, 0.9f * hp1.y);
    o1.z = fmaf(fmaxf(acc12 + nz1.z, 0.f), 0.1f, 0.9f * hp1.z);
    o1.w = fmaf(fmaxf(acc13 + nz1.w, 0.f), 0.1f, 0.9f * hp1.w);
    o2.x = fmaf(fmaxf(acc20 + nz2.x, 0.f), 0.1f, 0.9f * hp2.x);
    o2.y = fmaf(fmaxf(acc21 + nz2.y, 0.f), 0.1f, 0.9f * hp2.y);
    o2.z = fmaf(fmaxf(acc22 + nz2.z, 0.f), 0.1f, 0.9f * hp2.z);
    o2.w = fmaf(fmaxf(acc23 + nz2.w, 0.f), 0.1f, 0.9f * hp2.w);
    o3.x = fmaf(fmaxf(acc30 + nz3.x, 0.f), 0.1f, 0.9f * hp3.x);
    o3.y = fmaf(fmaxf(acc31 + nz3.y, 0.f), 0.1f, 0.9f * hp3.y);
    o3.z = fmaf(fmaxf(acc32 + nz3.z, 0.f), 0.1f, 0.9f * hp3.z);
    o3.w = fmaf(fmaxf(acc33 + nz3.w, 0.f), 0.1f, 0.9f * hp3.w);

    float* oh = out_h + (size_t)b0 * Tq * Hq + (size_t)t * Hq + j0;
    *(float4*)(oh)                       = o0;
    *(float4*)(oh + (size_t)Tq * Hq)     = o1;
    *(float4*)(oh + (size_t)2 * Tq * Hq) = o2;
    *(float4*)(oh + (size_t)3 * Tq * Hq) = o3;
    if (slabT) {
      float* sl = slabT + (size_t)b0 * Hq + j0;
      *(float4*)(sl)            = o0;
      *(float4*)(sl + Hq)       = o1;
      *(float4*)(sl + 2 * Hq)   = o2;
      *(float4*)(sl + 3 * Hq)   = o3;
    }
  }
}

extern "C" void kernel_launch(void* const* d_in, const int* in_sizes, int n_in,
                              void* d_out, int out_size, void* d_ws, size_t ws_size,
                              hipStream_t stream) {
  const float* x     = (const float*)d_in[0];
  const float* noise = (const float*)d_in[1];
  const float* Wi2h  = (const float*)d_in[2];
  const float* Wrec  = (const float*)d_in[3];
  const float* Wh2o  = (const float*)d_in[4];
  float* out_h = (float*)d_out;
  float* out_o = out_h + (size_t)Bq * Tq * Hq;

  const bool use_ws = ws_size >= (size_t)2 * Bq * Hq * sizeof(float);
  float* slab0 = (float*)d_ws;
  float* slab1 = slab0 + (size_t)Bq * Hq;

  for (int t = 0; t < Tq; ++t) {
    const float* sp = (t > 0 && use_ws) ? (((t - 1) & 1) ? slab1 : slab0) : nullptr;
    float*       st = use_ws ? ((t & 1) ? slab1 : slab0) : nullptr;
    rnn_step<<<256, 512, 0, stream>>>(x, noise, Wi2h, Wrec, Wh2o,
                                      out_h, out_o, sp, st, t);
  }
  const float* hb = use_ws ? slab1 : (out_h + (size_t)(Tq - 1) * Hq);
  const size_t rs = use_ws ? (size_t)Hq : (size_t)Tq * Hq;
  proj_tail<<<4, 256, 0, stream>>>(hb, rs, Wh2o, out_o, Tq - 1);
}